// Round 15
// baseline (86.596 us; speedup 1.0000x reference)
//
#include <hip/hip_runtime.h>
#include <math.h>

#define B_      32
#define NP1     2001
#define D_      512
#define R_      6
#define NROLES  190
#define NVERBS  504
#define VOCAB   2001
#define NREG    2000

#define NSPLIT  32
#define CHUNK   64
#define PSTRIDE 3592        // 6*512 (SW) + 512 (rsum) + 8 (sumexp+pad)
#define NUQ     16          // u-partial splits
// workspace layout (floats)
#define WS_U    8                        // 16*190 = 3040 floats
#define WS_PART 3048
#define WS_AB   (3048 + 3678208)         // ushort A_bf16[192*512] = 98304 ushort = 49152 floats
#define WS_WLB  (WS_AB + 49152)          // ushort Wlb[2048*512]

typedef __attribute__((ext_vector_type(8))) short  short8v;
typedef __attribute__((ext_vector_type(8))) unsigned short ushort8v;
typedef __attribute__((ext_vector_type(4))) float  f32x4;

__device__ __forceinline__ float fast_tanh(float x) {
    float e = exp2f(x * 2.885390082f);
    return 1.0f - 2.0f * __builtin_amdgcn_rcpf(e + 1.0f);
}
__device__ __forceinline__ float fast_exp(float x) {
    return exp2f(x * 1.442695041f);
}
__device__ __forceinline__ unsigned short f2bf(float f) {   // RNE
    unsigned u = __float_as_uint(f);
    return (unsigned short)((u + 0x7FFFu + ((u >> 16) & 1u)) >> 16);
}

// 64-lane sum, all lanes get result. 4 DPP (VALU) + ds_swizzle + shfl.
__device__ __forceinline__ float wave_sum(float v) {
    int x;
    x = __builtin_amdgcn_update_dpp(0, __float_as_int(v), 0xB1, 0xF, 0xF, true);
    v += __int_as_float(x);
    x = __builtin_amdgcn_update_dpp(0, __float_as_int(v), 0x4E, 0xF, 0xF, true);
    v += __int_as_float(x);
    x = __builtin_amdgcn_update_dpp(0, __float_as_int(v), 0x124, 0xF, 0xF, true);
    v += __int_as_float(x);
    x = __builtin_amdgcn_update_dpp(0, __float_as_int(v), 0x128, 0xF, 0xF, true);
    v += __int_as_float(x);
    x = __builtin_amdgcn_ds_swizzle(__float_as_int(v), 0x401F);
    v += __int_as_float(x);
    v += __shfl_xor(v, 32, 64);
    return v;
}

// async global->LDS, 16B/lane; LDS dest = l + lane*16 (HW adds lane offset)
__device__ __forceinline__ void gload_lds16(const float* g, float* l) {
    __builtin_amdgcn_global_load_lds(
        (const __attribute__((address_space(1))) void*)g,
        (__attribute__((address_space(3))) void*)l, 16, 0, 0);
}

// ---------------- K0: u[q][k] = sum_{d in q*32..} Wr[d][k]*Wa[d] ----------------
__global__ __launch_bounds__(256) void k0_upart(
    const float* __restrict__ Wr, const float* __restrict__ Wa,
    float* __restrict__ ws_u) {
    const int q = blockIdx.x;           // 16 blocks, 32 d each
    const int k = threadIdx.x;
    if (k >= NROLES) return;
    float s = 0.f;
    const int d0 = q * 32;
    #pragma unroll 8
    for (int d = 0; d < 32; ++d)
        s += Wr[(size_t)(d0 + d) * NROLES + k] * Wa[d0 + d];
    ws_u[q * NROLES + k] = s;
}

// ---------------- K1: {fused main pass (1024 blk)} ∪ {Wl cast (512)} ∪ {verb (64)} ----------------
// Main pass is software-pipelined: wave_sum(pair p)'s DS latency overlaps the
// tanh/exp/acc FMA block of pair p-1 (carried in ~20 extra VGPRs; 60->~80, still 4 blk/CU).
__global__ __launch_bounds__(256, 4) void k1_fused(
    const float* __restrict__ vs, const float* __restrict__ Wa,
    const float* __restrict__ roles, const float* __restrict__ br,
    const float* __restrict__ ba, const float* __restrict__ ws_u,
    float* __restrict__ part,
    const float* __restrict__ Wl, unsigned short* __restrict__ Wlb,
    const float* __restrict__ Wv, const float* __restrict__ bv,
    float* __restrict__ out_verb) {
    const int bid = blockIdx.x;
    const int tid = threadIdx.x;

    __shared__ __align__(16) float smem[4 * 2 * 1024];   // 32 KB rings; reused for merge / verb a_s
    __shared__ float lse_[4][R_];

    if (bid >= B_ * NSPLIT) {
        if (bid < B_ * NSPLIT + 512) {
            // ---- Wl cast: 2048 rows (pad >=2001 with 0), 512 cols ----
            const int ci = bid - B_ * NSPLIT;
            const int idx = ci * 2048 + tid * 8;
            const int row = idx >> 9;
            const int col = idx & 511;
            ushort8v o;
            if (row < VOCAB) {
                float4 a = *reinterpret_cast<const float4*>(Wl + (size_t)row * D_ + col);
                float4 b = *reinterpret_cast<const float4*>(Wl + (size_t)row * D_ + col + 4);
                o[0] = f2bf(a.x); o[1] = f2bf(a.y); o[2] = f2bf(a.z); o[3] = f2bf(a.w);
                o[4] = f2bf(b.x); o[5] = f2bf(b.y); o[6] = f2bf(b.z); o[7] = f2bf(b.w);
            } else {
                o = (ushort8v)0;
            }
            *reinterpret_cast<ushort8v*>(Wlb + idx) = o;
        } else {
            // ---- verb head ----
            const int q = bid - (B_ * NSPLIT + 512);   // 0..63
            const int b = q >> 1;
            const int g = q & 1;
            float* a_s = smem;
            float2 x = reinterpret_cast<const float2*>(vs + (size_t)b * (NP1 * D_))[tid];
            reinterpret_cast<float2*>(a_s)[tid] = make_float2(fmaxf(x.x, 0.f), fmaxf(x.y, 0.f));
            __syncthreads();
            const int v = g * 252 + tid;
            if (tid < 252 && v < NVERBS) {
                const float* wrow = Wv + (size_t)v * D_;
                float s = 0.f;
                #pragma unroll 4
                for (int k = 0; k < D_; k += 4) {
                    float4 w4 = *reinterpret_cast<const float4*>(wrow + k);
                    s += a_s[k] * w4.x + a_s[k + 1] * w4.y + a_s[k + 2] * w4.z + a_s[k + 3] * w4.w;
                }
                out_verb[b * NVERBS + v] = s + bv[v];
            }
        }
        return;
    }

    const int b     = bid / NSPLIT;
    const int split = bid % NSPLIT;
    const int lane  = tid & 63;
    const int w     = tid >> 6;
    float* ring = smem + w * 2048;

    const float4 wvA = *reinterpret_cast<const float4*>(Wa + D_ + lane * 4);
    const float4 wvB = *reinterpret_cast<const float4*>(Wa + D_ + 256 + lane * 4);

    const float* base = vs + (size_t)b * (NP1 * D_) + D_;
    const int n0 = split * CHUNK;
    const int nrows = min(n0 + CHUNK, NREG) - n0;    // 64 or 16
    const int cnt = (nrows - w + 3) >> 2;            // rows this wave (16 or 4)
    const int npairs = cnt >> 1;                     // 8 or 2

    // ---- stage first: get memory moving before the sr compute ----
    #pragma unroll
    for (int k = 0; k < 2; ++k) {
        const float* g0 = base + (size_t)(n0 + w + 8 * k) * D_ + lane * 4;
        float* s0 = ring + k * 1024;
        gload_lds16(g0, s0);
        gload_lds16(g0 + 256, s0 + 256);
        const float* g1 = g0 + 4 * D_;
        gload_lds16(g1, s0 + 512);
        gload_lds16(g1 + 256, s0 + 768);
    }
    asm volatile("" ::: "memory");

    // ---- inline s_role (L2-resident reads; overlaps ring latency) ----
    float sr[R_];
    {
        float pr[R_] = {0.f, 0.f, 0.f, 0.f, 0.f, 0.f};
        #pragma unroll
        for (int i = 0; i < 3; ++i) {
            const int k = lane + i * 64;
            if (k < NROLES) {
                float u = 0.f;
                #pragma unroll
                for (int q = 0; q < NUQ; ++q) u += ws_u[q * NROLES + k];
                #pragma unroll
                for (int r = 0; r < R_; ++r) pr[r] += roles[r * NROLES + k] * u;
            }
        }
        float c0 = 0.f;
        #pragma unroll
        for (int i = 0; i < 8; ++i) c0 += Wa[lane + i * 64] * br[lane + i * 64];
        c0 = wave_sum(c0) + ba[0];
        #pragma unroll
        for (int r = 0; r < R_; ++r) sr[r] = wave_sum(pr[r]) + c0;
    }

    float acc[R_][8];
    float rsum[8];
    float sume[R_];
    #pragma unroll
    for (int r = 0; r < R_; ++r) {
        sume[r] = 0.f;
        #pragma unroll
        for (int j = 0; j < 8; ++j) acc[r][j] = 0.f;
    }
    #pragma unroll
    for (int j = 0; j < 8; ++j) rsum[j] = 0.f;

    asm volatile("" ::: "memory");

    int st = 2;
    // ---- peel pair 0: load + dot + wave_sum (carried into the loop) ----
    float d0p, d1p;
    float xs0p[8], xs1p[8];
    {
        asm volatile("s_waitcnt vmcnt(4)" ::: "memory");
        const float* l0 = ring;                       // slot 0
        float4 x0A = *reinterpret_cast<const float4*>(l0 + lane * 4);
        float4 x0B = *reinterpret_cast<const float4*>(l0 + 256 + lane * 4);
        float4 x1A = *reinterpret_cast<const float4*>(l0 + 512 + lane * 4);
        float4 x1B = *reinterpret_cast<const float4*>(l0 + 768 + lane * 4);
        float d0 = x0A.x*wvA.x + x0A.y*wvA.y + x0A.z*wvA.z + x0A.w*wvA.w
                 + x0B.x*wvB.x + x0B.y*wvB.y + x0B.z*wvB.z + x0B.w*wvB.w;
        float d1 = x1A.x*wvA.x + x1A.y*wvA.y + x1A.z*wvA.z + x1A.w*wvA.w
                 + x1B.x*wvB.x + x1B.y*wvB.y + x1B.z*wvB.z + x1B.w*wvB.w;
        if (st < npairs) {                 // refill slot 0 (just consumed)
            const float* g0 = base + (size_t)(n0 + w + 8 * st) * D_ + lane * 4;
            float* s0 = ring;
            gload_lds16(g0, s0);
            gload_lds16(g0 + 256, s0 + 256);
            const float* g1 = g0 + 4 * D_;
            gload_lds16(g1, s0 + 512);
            gload_lds16(g1 + 256, s0 + 768);
            ++st;
        }
        d0p = wave_sum(d0);
        d1p = wave_sum(d1);
        xs0p[0]=x0A.x; xs0p[1]=x0A.y; xs0p[2]=x0A.z; xs0p[3]=x0A.w;
        xs0p[4]=x0B.x; xs0p[5]=x0B.y; xs0p[6]=x0B.z; xs0p[7]=x0B.w;
        xs1p[0]=x1A.x; xs1p[1]=x1A.y; xs1p[2]=x1A.z; xs1p[3]=x1A.w;
        xs1p[4]=x1B.x; xs1p[5]=x1B.y; xs1p[6]=x1B.z; xs1p[7]=x1B.w;
    }

    for (int p = 1; p < npairs; ++p) {
        const int rem = npairs - p;       // outstanding pairs = min(2, rem)
        if (rem > 1) asm volatile("s_waitcnt vmcnt(4)" ::: "memory");
        else         asm volatile("s_waitcnt vmcnt(0)" ::: "memory");

        const float* l0 = ring + (p & 1) * 1024;
        float4 x0A = *reinterpret_cast<const float4*>(l0 + lane * 4);
        float4 x0B = *reinterpret_cast<const float4*>(l0 + 256 + lane * 4);
        float4 x1A = *reinterpret_cast<const float4*>(l0 + 512 + lane * 4);
        float4 x1B = *reinterpret_cast<const float4*>(l0 + 768 + lane * 4);
        // consume (forces lgkm wait) BEFORE overwriting the slot
        float d0c = x0A.x*wvA.x + x0A.y*wvA.y + x0A.z*wvA.z + x0A.w*wvA.w
                  + x0B.x*wvB.x + x0B.y*wvB.y + x0B.z*wvB.z + x0B.w*wvB.w;
        float d1c = x1A.x*wvA.x + x1A.y*wvA.y + x1A.z*wvA.z + x1A.w*wvA.w
                  + x1B.x*wvB.x + x1B.y*wvB.y + x1B.z*wvB.z + x1B.w*wvB.w;
        if (st < npairs) {                 // refill the slot just consumed
            const float* g0 = base + (size_t)(n0 + w + 8 * st) * D_ + lane * 4;
            float* s0 = ring + (st & 1) * 1024;
            gload_lds16(g0, s0);
            gload_lds16(g0 + 256, s0 + 256);
            const float* g1 = g0 + 4 * D_;
            gload_lds16(g1, s0 + 512);
            gload_lds16(g1 + 256, s0 + 768);
            ++st;
        }
        // wave_sum(cur) — its two DS-latency hops overlap the prev-pair FMA block below
        d0c = wave_sum(d0c);
        d1c = wave_sum(d1c);
        // ---- acc for PREVIOUS pair (independent of the in-flight wave_sum) ----
        #pragma unroll
        for (int r = 0; r < R_; ++r) {
            float t0 = fast_tanh(sr[r] + d0p);
            float t1 = fast_tanh(sr[r] + d1p);
            sume[r] += fast_exp(t0) + fast_exp(t1);
            #pragma unroll
            for (int j = 0; j < 8; ++j) acc[r][j] += t0 * xs0p[j] + t1 * xs1p[j];
        }
        #pragma unroll
        for (int j = 0; j < 8; ++j) rsum[j] += xs0p[j] + xs1p[j];
        // rotate carried state
        d0p = d0c; d1p = d1c;
        xs0p[0]=x0A.x; xs0p[1]=x0A.y; xs0p[2]=x0A.z; xs0p[3]=x0A.w;
        xs0p[4]=x0B.x; xs0p[5]=x0B.y; xs0p[6]=x0B.z; xs0p[7]=x0B.w;
        xs1p[0]=x1A.x; xs1p[1]=x1A.y; xs1p[2]=x1A.z; xs1p[3]=x1A.w;
        xs1p[4]=x1B.x; xs1p[5]=x1B.y; xs1p[6]=x1B.z; xs1p[7]=x1B.w;
    }
    // ---- drain: acc for the last pair ----
    #pragma unroll
    for (int r = 0; r < R_; ++r) {
        float t0 = fast_tanh(sr[r] + d0p);
        float t1 = fast_tanh(sr[r] + d1p);
        sume[r] += fast_exp(t0) + fast_exp(t1);
        #pragma unroll
        for (int j = 0; j < 8; ++j) acc[r][j] += t0 * xs0p[j] + t1 * xs1p[j];
    }
    #pragma unroll
    for (int j = 0; j < 8; ++j) rsum[j] += xs0p[j] + xs1p[j];

    // merge the 4 waves into smem[0..3583] (reused -> barrier first)
    __syncthreads();
    float* ls = smem;
    for (int ww = 0; ww < 4; ++ww) {
        if (w == ww) {
            #pragma unroll
            for (int j = 0; j < 8; ++j) {
                const int dd = (j < 4) ? (lane * 4 + j) : (256 + lane * 4 + (j - 4));
                if (ww == 0) {
                    #pragma unroll
                    for (int r = 0; r < R_; ++r) ls[r * D_ + dd] = acc[r][j];
                    ls[6 * D_ + dd] = rsum[j];
                } else {
                    #pragma unroll
                    for (int r = 0; r < R_; ++r) ls[r * D_ + dd] += acc[r][j];
                    ls[6 * D_ + dd] += rsum[j];
                }
            }
            if (lane == 0) {
                #pragma unroll
                for (int r = 0; r < R_; ++r) lse_[ww][r] = sume[r];
            }
        }
        __syncthreads();
    }
    float* dst = part + (size_t)(b * NSPLIT + split) * PSTRIDE;
    for (int i = tid; i < 3584 / 4; i += 256)
        reinterpret_cast<float4*>(dst)[i] = reinterpret_cast<const float4*>(ls)[i];
    if (tid < R_)
        dst[3584 + tid] = lse_[0][tid] + lse_[1][tid] + lse_[2][tid] + lse_[3][tid];
}

// ---------------- K2: reduce partials -> relu(label_embed) as bf16 ----------------
__global__ __launch_bounds__(256) void k2_reduce(
    const float* __restrict__ part, unsigned short* __restrict__ AB) {
    const int bid = blockIdx.x;
    const int t = threadIdx.x;
    const int b = bid >> 3;
    const int chunk = bid & 7;
    const int dl = t & 63;
    const int qg = t >> 6;
    const int d = chunk * 64 + dl;
    const float* pb = part + (size_t)b * NSPLIT * PSTRIDE;

    float s[7] = {0.f, 0.f, 0.f, 0.f, 0.f, 0.f, 0.f};
    for (int q = qg * 8; q < qg * 8 + 8; ++q) {
        const float* p = pb + (size_t)q * PSTRIDE;
        #pragma unroll
        for (int r = 0; r < R_; ++r) s[r] += p[r * D_ + d];
        s[6] += p[6 * D_ + d];
    }
    __shared__ float red[4][7][64];
    #pragma unroll
    for (int i = 0; i < 7; ++i) red[qg][i][dl] = s[i];
    __shared__ float lse_s[R_];
    if (t < R_) {
        float se = 0.f;
        for (int q = 0; q < NSPLIT; ++q) se += pb[(size_t)q * PSTRIDE + 3584 + t];
        lse_s[t] = logf(se);
    }
    __syncthreads();
    if (t < 64) {
        float rs = red[0][6][dl] + red[1][6][dl] + red[2][6][dl] + red[3][6][dl];
        #pragma unroll
        for (int r = 0; r < R_; ++r) {
            float sw = red[0][r][dl] + red[1][r][dl] + red[2][r][dl] + red[3][r][dl];
            AB[(size_t)(b * R_ + r) * D_ + d] = f2bf(fmaxf(sw - lse_s[r] * rs, 0.f));
        }
    }
}

// ---------------- K3: bf16 MFMA gemm, out = relu(A) @ Wl^T + bl ----------------
// one wave-tile (16m x 64v) per 64-thread block; 384 blocks -> all CUs busy.
__global__ __launch_bounds__(64) void k3_mfma(
    const unsigned short* __restrict__ AB, const unsigned short* __restrict__ Wlb,
    const float* __restrict__ bl, float* __restrict__ out_role) {
    const int lane = threadIdx.x;
    const int wt   = blockIdx.x;             // 0..383
    const int mt   = wt >> 5;                // 0..11
    const int vt   = wt & 31;                // 0..31
    const int m0   = mt * 16;
    const int v0   = vt * 64;
    const int rc   = lane & 15;              // A-row (m) and B-col (v) sub-index
    const int kg   = lane >> 4;              // k-group

    const unsigned short* arow = AB + (size_t)(m0 + rc) * D_ + kg * 8;
    f32x4 acc0 = {0.f, 0.f, 0.f, 0.f}, acc1 = {0.f, 0.f, 0.f, 0.f};
    f32x4 acc2 = {0.f, 0.f, 0.f, 0.f}, acc3 = {0.f, 0.f, 0.f, 0.f};

    #pragma unroll 4
    for (int ks = 0; ks < 16; ++ks) {
        const int kb = ks * 32;
        short8v af = *reinterpret_cast<const short8v*>(arow + kb);
        const unsigned short* wb = Wlb + (size_t)(v0 + rc) * D_ + kg * 8 + kb;
        short8v b0 = *reinterpret_cast<const short8v*>(wb);
        short8v b1 = *reinterpret_cast<const short8v*>(wb + 16 * D_);
        short8v b2 = *reinterpret_cast<const short8v*>(wb + 32 * D_);
        short8v b3 = *reinterpret_cast<const short8v*>(wb + 48 * D_);
        acc0 = __builtin_amdgcn_mfma_f32_16x16x32_bf16(af, b0, acc0, 0, 0, 0);
        acc1 = __builtin_amdgcn_mfma_f32_16x16x32_bf16(af, b1, acc1, 0, 0, 0);
        acc2 = __builtin_amdgcn_mfma_f32_16x16x32_bf16(af, b2, acc2, 0, 0, 0);
        acc3 = __builtin_amdgcn_mfma_f32_16x16x32_bf16(af, b3, acc3, 0, 0, 0);
    }
    f32x4 accs[4] = {acc0, acc1, acc2, acc3};
    #pragma unroll
    for (int f = 0; f < 4; ++f) {
        const int v = v0 + f * 16 + rc;
        if (v < VOCAB) {
            const float bb = bl[v];
            #pragma unroll
            for (int j = 0; j < 4; ++j) {
                const int m = m0 + kg * 4 + j;
                out_role[(size_t)m * VOCAB + v] = accs[f][j] + bb;
            }
        }
    }
}

extern "C" void kernel_launch(void* const* d_in, const int* in_sizes, int n_in,
                              void* d_out, int out_size, void* d_ws, size_t ws_size,
                              hipStream_t stream) {
    const float* vs    = (const float*)d_in[0];
    const float* roles = (const float*)d_in[1];
    const float* Wr    = (const float*)d_in[2];
    const float* br    = (const float*)d_in[3];
    const float* Wa    = (const float*)d_in[4];
    const float* ba    = (const float*)d_in[5];
    const float* Wv    = (const float*)d_in[6];
    const float* bv    = (const float*)d_in[7];
    const float* Wl    = (const float*)d_in[8];
    const float* bl    = (const float*)d_in[9];

    float* out_verb = (float*)d_out;
    float* out_role = (float*)d_out + B_ * NVERBS;
    float* ws       = (float*)d_ws;
    unsigned short* AB  = (unsigned short*)(ws + WS_AB);
    unsigned short* Wlb = (unsigned short*)(ws + WS_WLB);

    k0_upart<<<dim3(NUQ), dim3(256), 0, stream>>>(Wr, Wa, ws + WS_U);
    k1_fused<<<dim3(B_ * NSPLIT + 512 + 64), dim3(256), 0, stream>>>(
        vs, Wa, roles, br, ba, ws + WS_U, ws + WS_PART,
        Wl, Wlb, Wv, bv, out_verb);
    k2_reduce<<<dim3(256), dim3(256), 0, stream>>>(ws + WS_PART, AB);
    k3_mfma<<<dim3(384), dim3(64), 0, stream>>>(AB, Wlb, bl, out_role);
}

// Round 16
// 61.852 us; speedup vs baseline: 1.4001x; 1.4001x over previous
//
#include <hip/hip_runtime.h>
#include <math.h>

#define B_      32
#define NP1     2001
#define D_      512
#define R_      6
#define NROLES  190
#define NVERBS  504
#define VOCAB   2001
#define NREG    2000

#define NSPLIT  32
#define CHUNK   64
#define PSTRIDE 3592        // 6*512 (SW) + 512 (rsum) + 8 (sumexp+pad)
#define NUQ     16          // u-partial splits
// workspace layout (floats)
#define WS_U    8                        // 16*190 = 3040 floats
#define WS_PART 3048
#define WS_AB   (3048 + 3678208)         // ushort A_bf16[192*512] = 98304 ushort = 49152 floats
#define WS_WLB  (WS_AB + 49152)          // ushort Wlb[2048*512]

typedef __attribute__((ext_vector_type(8))) short  short8v;
typedef __attribute__((ext_vector_type(8))) unsigned short ushort8v;
typedef __attribute__((ext_vector_type(4))) float  f32x4;
typedef __attribute__((ext_vector_type(2))) unsigned int uint2v;

__device__ __forceinline__ float fast_tanh(float x) {
    float e = exp2f(x * 2.885390082f);
    return 1.0f - 2.0f * __builtin_amdgcn_rcpf(e + 1.0f);
}
__device__ __forceinline__ float fast_exp(float x) {
    return exp2f(x * 1.442695041f);
}
__device__ __forceinline__ unsigned short f2bf(float f) {   // RNE
    unsigned u = __float_as_uint(f);
    return (unsigned short)((u + 0x7FFFu + ((u >> 16) & 1u)) >> 16);
}

// 64-lane sum, all lanes get result. PURE VALU: 4 DPP + permlane16_swap +
// permlane32_swap (gfx950). Zero DS ops -> ~30 cyc latency vs ~250 before.
__device__ __forceinline__ float wave_sum(float v) {
    int x;
    x = __builtin_amdgcn_update_dpp(0, __float_as_int(v), 0xB1, 0xF, 0xF, true);  // xor1 (quad)
    v += __int_as_float(x);
    x = __builtin_amdgcn_update_dpp(0, __float_as_int(v), 0x4E, 0xF, 0xF, true);  // xor2 (quad)
    v += __int_as_float(x);
    x = __builtin_amdgcn_update_dpp(0, __float_as_int(v), 0x124, 0xF, 0xF, true); // row_ror:4
    v += __int_as_float(x);
    x = __builtin_amdgcn_update_dpp(0, __float_as_int(v), 0x128, 0xF, 0xF, true); // row_ror:8
    v += __int_as_float(x);
    // rows (16-lane groups) each hold their row sum; combine rows VALU-only:
    uint2v p = __builtin_amdgcn_permlane16_swap(__float_as_uint(v), __float_as_uint(v), false, false);
    v = __uint_as_float(p[0]) + __uint_as_float(p[1]);   // row pairs summed
    p = __builtin_amdgcn_permlane32_swap(__float_as_uint(v), __float_as_uint(v), false, false);
    v = __uint_as_float(p[0]) + __uint_as_float(p[1]);   // halves summed
    return v;
}

// async global->LDS, 16B/lane; LDS dest = l + lane*16 (HW adds lane offset)
__device__ __forceinline__ void gload_lds16(const float* g, float* l) {
    __builtin_amdgcn_global_load_lds(
        (const __attribute__((address_space(1))) void*)g,
        (__attribute__((address_space(3))) void*)l, 16, 0, 0);
}

// ---------------- K0: u[q][k] = sum_{d in q*32..} Wr[d][k]*Wa[d] ----------------
__global__ __launch_bounds__(256) void k0_upart(
    const float* __restrict__ Wr, const float* __restrict__ Wa,
    float* __restrict__ ws_u) {
    const int q = blockIdx.x;           // 16 blocks, 32 d each
    const int k = threadIdx.x;
    if (k >= NROLES) return;
    float s = 0.f;
    const int d0 = q * 32;
    #pragma unroll 8
    for (int d = 0; d < 32; ++d)
        s += Wr[(size_t)(d0 + d) * NROLES + k] * Wa[d0 + d];
    ws_u[q * NROLES + k] = s;
}

// ---------------- K1: {fused main pass (1024 blk)} ∪ {Wl cast (512)} ∪ {verb (64)} ----------------
// cast/verb blocks backfill CU slots as main-pass blocks retire (overlap, not serial).
__global__ __launch_bounds__(256, 4) void k1_fused(
    const float* __restrict__ vs, const float* __restrict__ Wa,
    const float* __restrict__ roles, const float* __restrict__ br,
    const float* __restrict__ ba, const float* __restrict__ ws_u,
    float* __restrict__ part,
    const float* __restrict__ Wl, unsigned short* __restrict__ Wlb,
    const float* __restrict__ Wv, const float* __restrict__ bv,
    float* __restrict__ out_verb) {
    const int bid = blockIdx.x;
    const int tid = threadIdx.x;

    __shared__ __align__(16) float smem[4 * 2 * 1024];   // 32 KB rings; reused for merge / verb a_s
    __shared__ float lse_[4][R_];

    if (bid >= B_ * NSPLIT) {
        if (bid < B_ * NSPLIT + 512) {
            // ---- Wl cast: 2048 rows (pad >=2001 with 0), 512 cols ----
            const int ci = bid - B_ * NSPLIT;
            const int idx = ci * 2048 + tid * 8;
            const int row = idx >> 9;
            const int col = idx & 511;
            ushort8v o;
            if (row < VOCAB) {
                float4 a = *reinterpret_cast<const float4*>(Wl + (size_t)row * D_ + col);
                float4 b = *reinterpret_cast<const float4*>(Wl + (size_t)row * D_ + col + 4);
                o[0] = f2bf(a.x); o[1] = f2bf(a.y); o[2] = f2bf(a.z); o[3] = f2bf(a.w);
                o[4] = f2bf(b.x); o[5] = f2bf(b.y); o[6] = f2bf(b.z); o[7] = f2bf(b.w);
            } else {
                o = (ushort8v)0;
            }
            *reinterpret_cast<ushort8v*>(Wlb + idx) = o;
        } else {
            // ---- verb head ----
            const int q = bid - (B_ * NSPLIT + 512);   // 0..63
            const int b = q >> 1;
            const int g = q & 1;
            float* a_s = smem;
            float2 x = reinterpret_cast<const float2*>(vs + (size_t)b * (NP1 * D_))[tid];
            reinterpret_cast<float2*>(a_s)[tid] = make_float2(fmaxf(x.x, 0.f), fmaxf(x.y, 0.f));
            __syncthreads();
            const int v = g * 252 + tid;
            if (tid < 252 && v < NVERBS) {
                const float* wrow = Wv + (size_t)v * D_;
                float s = 0.f;
                #pragma unroll 4
                for (int k = 0; k < D_; k += 4) {
                    float4 w4 = *reinterpret_cast<const float4*>(wrow + k);
                    s += a_s[k] * w4.x + a_s[k + 1] * w4.y + a_s[k + 2] * w4.z + a_s[k + 3] * w4.w;
                }
                out_verb[b * NVERBS + v] = s + bv[v];
            }
        }
        return;
    }

    const int b     = bid / NSPLIT;
    const int split = bid % NSPLIT;
    const int lane  = tid & 63;
    const int w     = tid >> 6;
    float* ring = smem + w * 2048;

    const float4 wvA = *reinterpret_cast<const float4*>(Wa + D_ + lane * 4);
    const float4 wvB = *reinterpret_cast<const float4*>(Wa + D_ + 256 + lane * 4);

    const float* base = vs + (size_t)b * (NP1 * D_) + D_;
    const int n0 = split * CHUNK;
    const int nrows = min(n0 + CHUNK, NREG) - n0;    // 64 or 16
    const int cnt = (nrows - w + 3) >> 2;            // rows this wave (16 or 4)
    const int npairs = cnt >> 1;                     // 8 or 2

    // ---- stage first: get memory moving before the sr compute ----
    #pragma unroll
    for (int k = 0; k < 2; ++k) {
        const float* g0 = base + (size_t)(n0 + w + 8 * k) * D_ + lane * 4;
        float* s0 = ring + k * 1024;
        gload_lds16(g0, s0);
        gload_lds16(g0 + 256, s0 + 256);
        const float* g1 = g0 + 4 * D_;
        gload_lds16(g1, s0 + 512);
        gload_lds16(g1 + 256, s0 + 768);
    }
    asm volatile("" ::: "memory");

    // ---- inline s_role (L2-resident reads; overlaps ring latency) ----
    float sr[R_];
    {
        float pr[R_] = {0.f, 0.f, 0.f, 0.f, 0.f, 0.f};
        #pragma unroll
        for (int i = 0; i < 3; ++i) {
            const int k = lane + i * 64;
            if (k < NROLES) {
                float u = 0.f;
                #pragma unroll
                for (int q = 0; q < NUQ; ++q) u += ws_u[q * NROLES + k];
                #pragma unroll
                for (int r = 0; r < R_; ++r) pr[r] += roles[r * NROLES + k] * u;
            }
        }
        float c0 = 0.f;
        #pragma unroll
        for (int i = 0; i < 8; ++i) c0 += Wa[lane + i * 64] * br[lane + i * 64];
        c0 = wave_sum(c0) + ba[0];
        #pragma unroll
        for (int r = 0; r < R_; ++r) sr[r] = wave_sum(pr[r]) + c0;
    }

    float acc[R_][8];
    float rsum[8];
    float sume[R_];
    #pragma unroll
    for (int r = 0; r < R_; ++r) {
        sume[r] = 0.f;
        #pragma unroll
        for (int j = 0; j < 8; ++j) acc[r][j] = 0.f;
    }
    #pragma unroll
    for (int j = 0; j < 8; ++j) rsum[j] = 0.f;

    asm volatile("" ::: "memory");

    int st = 2;
    for (int p = 0; p < npairs; ++p) {
        const int rem = npairs - p;       // outstanding pairs = min(2, rem)
        if (rem > 1) asm volatile("s_waitcnt vmcnt(4)" ::: "memory");
        else         asm volatile("s_waitcnt vmcnt(0)" ::: "memory");

        const float* l0 = ring + (p & 1) * 1024;
        float4 x0A = *reinterpret_cast<const float4*>(l0 + lane * 4);
        float4 x0B = *reinterpret_cast<const float4*>(l0 + 256 + lane * 4);
        float4 x1A = *reinterpret_cast<const float4*>(l0 + 512 + lane * 4);
        float4 x1B = *reinterpret_cast<const float4*>(l0 + 768 + lane * 4);
        // consume (forces lgkm wait) BEFORE overwriting the slot
        float d0 = x0A.x*wvA.x + x0A.y*wvA.y + x0A.z*wvA.z + x0A.w*wvA.w
                 + x0B.x*wvB.x + x0B.y*wvB.y + x0B.z*wvB.z + x0B.w*wvB.w;
        float d1 = x1A.x*wvA.x + x1A.y*wvA.y + x1A.z*wvA.z + x1A.w*wvA.w
                 + x1B.x*wvB.x + x1B.y*wvB.y + x1B.z*wvB.z + x1B.w*wvB.w;
        if (st < npairs) {                 // refill the slot just consumed
            const float* g0 = base + (size_t)(n0 + w + 8 * st) * D_ + lane * 4;
            float* s0 = ring + (st & 1) * 1024;
            gload_lds16(g0, s0);
            gload_lds16(g0 + 256, s0 + 256);
            const float* g1 = g0 + 4 * D_;
            gload_lds16(g1, s0 + 512);
            gload_lds16(g1 + 256, s0 + 768);
            ++st;
        }
        d0 = wave_sum(d0);
        d1 = wave_sum(d1);
        float xs0[8] = {x0A.x,x0A.y,x0A.z,x0A.w,x0B.x,x0B.y,x0B.z,x0B.w};
        float xs1[8] = {x1A.x,x1A.y,x1A.z,x1A.w,x1B.x,x1B.y,x1B.z,x1B.w};
        #pragma unroll
        for (int r = 0; r < R_; ++r) {
            float t0 = fast_tanh(sr[r] + d0);
            float t1 = fast_tanh(sr[r] + d1);
            sume[r] += fast_exp(t0) + fast_exp(t1);
            #pragma unroll
            for (int j = 0; j < 8; ++j) acc[r][j] += t0 * xs0[j] + t1 * xs1[j];
        }
        #pragma unroll
        for (int j = 0; j < 8; ++j) rsum[j] += xs0[j] + xs1[j];
    }

    // merge the 4 waves into smem[0..3583] (reused -> barrier first)
    __syncthreads();
    float* ls = smem;
    for (int ww = 0; ww < 4; ++ww) {
        if (w == ww) {
            #pragma unroll
            for (int j = 0; j < 8; ++j) {
                const int dd = (j < 4) ? (lane * 4 + j) : (256 + lane * 4 + (j - 4));
                if (ww == 0) {
                    #pragma unroll
                    for (int r = 0; r < R_; ++r) ls[r * D_ + dd] = acc[r][j];
                    ls[6 * D_ + dd] = rsum[j];
                } else {
                    #pragma unroll
                    for (int r = 0; r < R_; ++r) ls[r * D_ + dd] += acc[r][j];
                    ls[6 * D_ + dd] += rsum[j];
                }
            }
            if (lane == 0) {
                #pragma unroll
                for (int r = 0; r < R_; ++r) lse_[ww][r] = sume[r];
            }
        }
        __syncthreads();
    }
    float* dst = part + (size_t)(b * NSPLIT + split) * PSTRIDE;
    for (int i = tid; i < 3584 / 4; i += 256)
        reinterpret_cast<float4*>(dst)[i] = reinterpret_cast<const float4*>(ls)[i];
    if (tid < R_)
        dst[3584 + tid] = lse_[0][tid] + lse_[1][tid] + lse_[2][tid] + lse_[3][tid];
}

// ---------------- K2: reduce partials -> relu(label_embed) as bf16 ----------------
__global__ __launch_bounds__(256) void k2_reduce(
    const float* __restrict__ part, unsigned short* __restrict__ AB) {
    const int bid = blockIdx.x;
    const int t = threadIdx.x;
    const int b = bid >> 3;
    const int chunk = bid & 7;
    const int dl = t & 63;
    const int qg = t >> 6;
    const int d = chunk * 64 + dl;
    const float* pb = part + (size_t)b * NSPLIT * PSTRIDE;

    float s[7] = {0.f, 0.f, 0.f, 0.f, 0.f, 0.f, 0.f};
    for (int q = qg * 8; q < qg * 8 + 8; ++q) {
        const float* p = pb + (size_t)q * PSTRIDE;
        #pragma unroll
        for (int r = 0; r < R_; ++r) s[r] += p[r * D_ + d];
        s[6] += p[6 * D_ + d];
    }
    __shared__ float red[4][7][64];
    #pragma unroll
    for (int i = 0; i < 7; ++i) red[qg][i][dl] = s[i];
    __shared__ float lse_s[R_];
    if (t < R_) {
        float se = 0.f;
        for (int q = 0; q < NSPLIT; ++q) se += pb[(size_t)q * PSTRIDE + 3584 + t];
        lse_s[t] = logf(se);
    }
    __syncthreads();
    if (t < 64) {
        float rs = red[0][6][dl] + red[1][6][dl] + red[2][6][dl] + red[3][6][dl];
        #pragma unroll
        for (int r = 0; r < R_; ++r) {
            float sw = red[0][r][dl] + red[1][r][dl] + red[2][r][dl] + red[3][r][dl];
            AB[(size_t)(b * R_ + r) * D_ + d] = f2bf(fmaxf(sw - lse_s[r] * rs, 0.f));
        }
    }
}

// ---------------- K3: bf16 MFMA gemm, out = relu(A) @ Wl^T + bl ----------------
// one wave-tile (16m x 64v) per 64-thread block; 384 blocks -> all CUs busy.
__global__ __launch_bounds__(64) void k3_mfma(
    const unsigned short* __restrict__ AB, const unsigned short* __restrict__ Wlb,
    const float* __restrict__ bl, float* __restrict__ out_role) {
    const int lane = threadIdx.x;
    const int wt   = blockIdx.x;             // 0..383
    const int mt   = wt >> 5;                // 0..11
    const int vt   = wt & 31;                // 0..31
    const int m0   = mt * 16;
    const int v0   = vt * 64;
    const int rc   = lane & 15;              // A-row (m) and B-col (v) sub-index
    const int kg   = lane >> 4;              // k-group

    const unsigned short* arow = AB + (size_t)(m0 + rc) * D_ + kg * 8;
    f32x4 acc0 = {0.f, 0.f, 0.f, 0.f}, acc1 = {0.f, 0.f, 0.f, 0.f};
    f32x4 acc2 = {0.f, 0.f, 0.f, 0.f}, acc3 = {0.f, 0.f, 0.f, 0.f};

    #pragma unroll 4
    for (int ks = 0; ks < 16; ++ks) {
        const int kb = ks * 32;
        short8v af = *reinterpret_cast<const short8v*>(arow + kb);
        const unsigned short* wb = Wlb + (size_t)(v0 + rc) * D_ + kg * 8 + kb;
        short8v b0 = *reinterpret_cast<const short8v*>(wb);
        short8v b1 = *reinterpret_cast<const short8v*>(wb + 16 * D_);
        short8v b2 = *reinterpret_cast<const short8v*>(wb + 32 * D_);
        short8v b3 = *reinterpret_cast<const short8v*>(wb + 48 * D_);
        acc0 = __builtin_amdgcn_mfma_f32_16x16x32_bf16(af, b0, acc0, 0, 0, 0);
        acc1 = __builtin_amdgcn_mfma_f32_16x16x32_bf16(af, b1, acc1, 0, 0, 0);
        acc2 = __builtin_amdgcn_mfma_f32_16x16x32_bf16(af, b2, acc2, 0, 0, 0);
        acc3 = __builtin_amdgcn_mfma_f32_16x16x32_bf16(af, b3, acc3, 0, 0, 0);
    }
    f32x4 accs[4] = {acc0, acc1, acc2, acc3};
    #pragma unroll
    for (int f = 0; f < 4; ++f) {
        const int v = v0 + f * 16 + rc;
        if (v < VOCAB) {
            const float bb = bl[v];
            #pragma unroll
            for (int j = 0; j < 4; ++j) {
                const int m = m0 + kg * 4 + j;
                out_role[(size_t)m * VOCAB + v] = accs[f][j] + bb;
            }
        }
    }
}

extern "C" void kernel_launch(void* const* d_in, const int* in_sizes, int n_in,
                              void* d_out, int out_size, void* d_ws, size_t ws_size,
                              hipStream_t stream) {
    const float* vs    = (const float*)d_in[0];
    const float* roles = (const float*)d_in[1];
    const float* Wr    = (const float*)d_in[2];
    const float* br    = (const float*)d_in[3];
    const float* Wa    = (const float*)d_in[4];
    const float* ba    = (const float*)d_in[5];
    const float* Wv    = (const float*)d_in[6];
    const float* bv    = (const float*)d_in[7];
    const float* Wl    = (const float*)d_in[8];
    const float* bl    = (const float*)d_in[9];

    float* out_verb = (float*)d_out;
    float* out_role = (float*)d_out + B_ * NVERBS;
    float* ws       = (float*)d_ws;
    unsigned short* AB  = (unsigned short*)(ws + WS_AB);
    unsigned short* Wlb = (unsigned short*)(ws + WS_WLB);

    k0_upart<<<dim3(NUQ), dim3(256), 0, stream>>>(Wr, Wa, ws + WS_U);
    k1_fused<<<dim3(B_ * NSPLIT + 512 + 64), dim3(256), 0, stream>>>(
        vs, Wa, roles, br, ba, ws + WS_U, ws + WS_PART,
        Wl, Wlb, Wv, bv, out_verb);
    k2_reduce<<<dim3(256), dim3(256), 0, stream>>>(ws + WS_PART, AB);
    k3_mfma<<<dim3(384), dim3(64), 0, stream>>>(AB, Wlb, bl, out_role);
}